// Round 8
// baseline (495.985 us; speedup 1.0000x reference)
//
#include <hip/hip_runtime.h>
#include <hip/hip_bf16.h>

// Problem constants: x is (N=16, C=64, H=512, W=512) float32, LEVEL_NUM=16.
#define NB   16
#define CB   64
#define HH   512
#define WW   512
#define HWP  (HH*WW)          // 262144 pixels per (n,c)
#define HWP4 (HWP/4)          // 65536 float4 per (n,c)
#define LEV  16

// 12-bit code planes: per (n,c) plane, 262144 px = 32768 groups of 8 px.
// Each group -> 3 dwords, stored in 3 SPLIT planes (d0,d1,d2) so encode
// stores and decode loads are lane-dense.
#define PLANE_G  32768                 // groups per (n,c) plane
#define PLANE_DW (3*PLANE_G)           // 98304 dwords per (n,c) plane
#define CODES_DW ((size_t)NB*CB*PLANE_DW)

typedef __attribute__((ext_vector_type(8))) short    short8;
typedef __attribute__((ext_vector_type(4))) float    f32x4;
typedef __attribute__((ext_vector_type(4))) unsigned u32x4;
typedef __attribute__((ext_vector_type(2))) unsigned u32x2;

// ---- helpers -------------------------------------------------------------

__device__ inline float wred_sum(float v){
  #pragma unroll
  for (int m = 32; m > 0; m >>= 1) v += __shfl_xor(v, m, 64);
  return v;
}
__device__ inline float wred_min(float v){
  #pragma unroll
  for (int m = 32; m > 0; m >>= 1) v = fminf(v, __shfl_xor(v, m, 64));
  return v;
}
__device__ inline float wred_max(float v){
  #pragma unroll
  for (int m = 32; m > 0; m >>= 1) v = fmaxf(v, __shfl_xor(v, m, 64));
  return v;
}

// monotonic float<->uint mapping so we can use atomicMin/Max on unsigned
__device__ inline unsigned fl(float f){
  unsigned b = __float_as_uint(f);
  return (b & 0x80000000u) ? ~b : (b | 0x80000000u);
}
__device__ inline float unfl(unsigned u){
  unsigned b = (u & 0x80000000u) ? (u ^ 0x80000000u) : ~u;
  return __uint_as_float(b);
}

#define C3 (-0.022542110013890053f)   // -(sigma^2)*log2(e), sigma^2 = 1/64

__device__ inline float qexp(float v, float q){
  float d = v - q; return exp2f(C3 * d * d);
}
// pack two f32 -> one u32 of 2x bf16 (RNE) via hardware v_cvt_pk_bf16_f32
__device__ inline unsigned pkbf(float a, float b){
  __hip_bfloat162 h = __float22bfloat162_rn(float2{a, b});
  unsigned u; __builtin_memcpy(&u, &h, sizeof(u));
  return u;
}
// 12-bit fixed-point encode: q = round(x*256) + 2048, clamped [0,4095]
__device__ inline unsigned enc12(float x){
  float f = fmaf(x, 256.0f, 2048.5f);
  f = fminf(fmaxf(f, 0.0f), 4095.0f);
  return (unsigned)f;
}
// encode 8 px (two float4) -> 3 packed dwords
__device__ inline void enc8(f32x4 v0, f32x4 v1, unsigned* d){
  unsigned q0=enc12(v0[0]), q1=enc12(v0[1]), q2=enc12(v0[2]), q3=enc12(v0[3]);
  unsigned q4=enc12(v1[0]), q5=enc12(v1[1]), q6=enc12(v1[2]), q7=enc12(v1[3]);
  d[0] =  q0        | (q1 << 12) | (q2 << 24);
  d[1] = (q2 >>  8) | (q3 <<  4) | (q4 << 16) | (q5 << 28);
  d[2] = (q5 >>  4) | (q6 <<  8) | (q7 << 20);
}
// decode 8 px from the 3 split dwords -> centered code values (q-2048)
__device__ inline void dec8(unsigned d0, unsigned d1, unsigned d2, float* u){
  unsigned q0 =  d0        & 0xFFFu;
  unsigned q1 = (d0 >> 12) & 0xFFFu;
  unsigned q2 = ((d0 >> 24) | (d1 << 8)) & 0xFFFu;
  unsigned q3 = (d1 >>  4) & 0xFFFu;
  unsigned q4 = (d1 >> 16) & 0xFFFu;
  unsigned q5 = ((d1 >> 28) | (d2 << 4)) & 0xFFFu;
  unsigned q6 = (d2 >>  8) & 0xFFFu;
  unsigned q7 =  d2 >> 20;
  u[0]=(float)q0-2048.f; u[1]=(float)q1-2048.f; u[2]=(float)q2-2048.f;
  u[3]=(float)q3-2048.f; u[4]=(float)q4-2048.f; u[5]=(float)q5-2048.f;
  u[6]=(float)q6-2048.f; u[7]=(float)q7-2048.f;
}

// ---- ws layout (float/dword offsets) -------------------------------------
#define WS_SUMC  0                        // 1024 per-(n,c) channel sums
#define WS_MIN   2048                     // 16 uint (flipped)
#define WS_MAX   2064                     // 16 uint (flipped)
#define WS_COS   8192                     // 16*262144 cos map
#define WS_PARTS (WS_COS + NB*HWP)        // 512*256 sta partials
#define WS_CODES (WS_PARTS + 512*256)     // 12-bit code planes (~403 MB)

// ---- K1c: plane sums + 12-bit code write (first 1 GiB read) -------------
// 16 px/thread/iter: reads 4 KB/wave contiguous; NT u32x2 stores per plane.
__global__ void __launch_bounds__(256) k1c(const f32x4* __restrict__ xv,
                                           float* __restrict__ sumc,
                                           unsigned* __restrict__ codes,
                                           unsigned* __restrict__ mn,
                                           unsigned* __restrict__ mx){
  int nc = blockIdx.x;               // grid = 1024, one block per (n,c) plane
  int t  = threadIdx.x;
  if ((nc & 63) == 0 && t == 0){     // k1 completes before k2 reads these
    mn[nc >> 6] = 0xFFFFFFFFu;
    mx[nc >> 6] = 0u;
  }
  const f32x4* xb = xv + (size_t)nc * HWP4 + 4*t;
  unsigned* c0 = codes + (size_t)nc * PLANE_DW + 2*t;
  float s = 0.0f;
  #pragma unroll 2
  for (int k = 0; k < 64; ++k){      // 16 px per thread per iter
    f32x4 v0 = __builtin_nontemporal_load(xb + k*1024);
    f32x4 v1 = __builtin_nontemporal_load(xb + k*1024 + 1);
    f32x4 v2 = __builtin_nontemporal_load(xb + k*1024 + 2);
    f32x4 v3 = __builtin_nontemporal_load(xb + k*1024 + 3);
    s += ((v0[0]+v0[1])+(v0[2]+v0[3])) + ((v1[0]+v1[1])+(v1[2]+v1[3]))
       + ((v2[0]+v2[1])+(v2[2]+v2[3])) + ((v3[0]+v3[1])+(v3[2]+v3[3]));
    unsigned dA[3], dB[3];
    enc8(v0, v1, dA);                // group 2t   (px 16t..16t+7)
    enc8(v2, v3, dB);                // group 2t+1 (px 16t+8..16t+15)
    __builtin_nontemporal_store(u32x2{dA[0], dB[0]}, (u32x2*)(c0 + k*512));
    __builtin_nontemporal_store(u32x2{dA[1], dB[1]}, (u32x2*)(c0 + k*512 +   PLANE_G));
    __builtin_nontemporal_store(u32x2{dA[2], dB[2]}, (u32x2*)(c0 + k*512 + 2*PLANE_G));
  }
  s = wred_sum(s);
  __shared__ float sm[4];
  if ((t & 63) == 0) sm[t >> 6] = s;
  __syncthreads();
  if (t == 0) sumc[nc] = (sm[0]+sm[1])+(sm[2]+sm[3]);
}

// ---- K1p: plane sums only (fallback when ws too small) ------------------
__global__ void __launch_bounds__(256) k1p(const f32x4* __restrict__ xv,
                                           float* __restrict__ sumc,
                                           unsigned* __restrict__ mn,
                                           unsigned* __restrict__ mx){
  int nc = blockIdx.x;
  int t  = threadIdx.x;
  if ((nc & 63) == 0 && t == 0){ mn[nc >> 6] = 0xFFFFFFFFu; mx[nc >> 6] = 0u; }
  const f32x4* xb = xv + (size_t)nc * HWP4 + t;
  float s = 0.0f;
  #pragma unroll 8
  for (int k = 0; k < 256; ++k){
    f32x4 v = __builtin_nontemporal_load(xb + k*256);
    s += (v[0] + v[1]) + (v[2] + v[3]);
  }
  s = wred_sum(s);
  __shared__ float sm[4];
  if ((t & 63) == 0) sm[t >> 6] = s;
  __syncthreads();
  if (t == 0) sumc[nc] = (sm[0]+sm[1])+(sm[2]+sm[3]);
}

// ---- K2c: cosine from 12-bit codes (reads 0.4 GiB, not 1 GiB) -----------
// u32x4 plane loads: 16 B/lane -> 1 KB/wave/plane contiguous; 32 px/thread.
__global__ void __launch_bounds__(256) k2c(const unsigned* __restrict__ codes,
                                           const float* __restrict__ sumc,
                                           f32x4* __restrict__ cosv,
                                           unsigned* __restrict__ mn,
                                           unsigned* __restrict__ mx){
  int bid = blockIdx.x;              // grid = 16*32 = 512
  int n = bid >> 5, ch = bid & 31;
  int t = threadIdx.x;
  __shared__ float sa[CB];
  if (t < CB){                       // wave 0: normalized x_ave from sumc
    float val = sumc[n*CB + t] * (1.0f / (float)HWP);
    float s2 = wred_sum(val * val);
    sa[t] = val * (1.0f / fmaxf(sqrtf(s2), 1e-12f));
  }
  __syncthreads();

  int g0 = ch*1024 + 4*t;            // thread's 4 groups (32 px) per plane
  float dot[32], nrm[32];
  #pragma unroll
  for (int p = 0; p < 32; ++p){ dot[p] = 0.0f; nrm[p] = 0.0f; }

  const unsigned* cpn = codes + (size_t)n * CB * PLANE_DW + g0;
  for (int c = 0; c < CB; ++c){
    const unsigned* pl = cpn + (size_t)c * PLANE_DW;
    u32x4 a0 = __builtin_nontemporal_load((const u32x4*)pl);
    u32x4 a1 = __builtin_nontemporal_load((const u32x4*)(pl +   PLANE_G));
    u32x4 a2 = __builtin_nontemporal_load((const u32x4*)(pl + 2*PLANE_G));
    float u[32];
    #pragma unroll
    for (int gi = 0; gi < 4; ++gi) dec8(a0[gi], a1[gi], a2[gi], u + 8*gi);
    float ac = sa[c];
    #pragma unroll
    for (int p = 0; p < 32; ++p){
      dot[p] = fmaf(ac,   u[p], dot[p]);
      nrm[p] = fmaf(u[p], u[p], nrm[p]);
    }
  }

  // cos = dot_code / sqrt(nrm_code): the 1/256 LSB cancels.
  int pv0 = ch*2048 + t*8;           // float4 index of thread's 32 px
  float mnl = 2.0f, mxl = -2.0f;
  #pragma unroll
  for (int k = 0; k < 8; ++k){
    f32x4 cs;
    #pragma unroll
    for (int e = 0; e < 4; ++e){
      float cv = dot[k*4+e] / fmaxf(sqrtf(nrm[k*4+e]), 1e-6f);
      cs[e] = cv;
      mnl = fminf(mnl, cv); mxl = fmaxf(mxl, cv);
    }
    cosv[(size_t)n * HWP4 + pv0 + k] = cs;
  }

  mnl = wred_min(mnl); mxl = wred_max(mxl);
  __shared__ float smn[4], smx[4];
  if ((t & 63) == 0){ smn[t >> 6] = mnl; smx[t >> 6] = mxl; }
  __syncthreads();
  if (t == 0){
    float m0 = fminf(fminf(smn[0], smn[1]), fminf(smn[2], smn[3]));
    float M0 = fmaxf(fmaxf(smx[0], smx[1]), fmaxf(smx[2], smx[3]));
    atomicMin(&mn[n], fl(m0));
    atomicMax(&mx[n], fl(M0));
  }
}

// ---- K2f: cosine from fp32 x (fallback; second 1 GiB read) --------------
__global__ void __launch_bounds__(256) k2f(const f32x4* __restrict__ xv,
                                           const float* __restrict__ sumc,
                                           f32x4* __restrict__ cosv,
                                           unsigned* __restrict__ mn,
                                           unsigned* __restrict__ mx){
  int bid = blockIdx.x;              // grid = 16*64 = 1024
  int n = bid >> 6, ch = bid & 63;
  int t = threadIdx.x;
  int p0 = ch * 1024;
  __shared__ float sa[CB];
  if (t < CB){
    float val = sumc[n*CB + t] * (1.0f / (float)HWP);
    float s2 = wred_sum(val * val);
    sa[t] = val * (1.0f / fmaxf(sqrtf(s2), 1e-12f));
  }
  __syncthreads();

  f32x4 dot[4], nrm[4];
  #pragma unroll
  for (int k = 0; k < 4; ++k){ dot[k] = (f32x4){0,0,0,0}; nrm[k] = (f32x4){0,0,0,0}; }

  const f32x4* xn = xv + (size_t)n * CB * HWP4 + p0 + t;
  #pragma unroll 2
  for (int c = 0; c < CB; ++c){
    const f32x4* xb = xn + (size_t)c * HWP4;
    float a = sa[c];
    #pragma unroll
    for (int k = 0; k < 4; ++k){
      f32x4 v = __builtin_nontemporal_load(xb + k*256);
      dot[k] += a * v;
      nrm[k] += v * v;
    }
  }

  float mnl = 2.0f, mxl = -2.0f;
  #pragma unroll
  for (int k = 0; k < 4; ++k){
    f32x4 cs;
    #pragma unroll
    for (int e = 0; e < 4; ++e){
      cs[e] = dot[k][e] / fmaxf(sqrtf(nrm[k][e]), 1e-12f);
      mnl = fminf(mnl, cs[e]); mxl = fmaxf(mxl, cs[e]);
    }
    cosv[(size_t)n * HWP4 + p0 + k*256 + t] = cs;
  }

  mnl = wred_min(mnl); mxl = wred_max(mxl);
  __shared__ float smn[4], smx[4];
  if ((t & 63) == 0){ smn[t >> 6] = mnl; smx[t >> 6] = mxl; }
  __syncthreads();
  if (t == 0){
    float m0 = fminf(fminf(smn[0], smn[1]), fminf(smn[2], smn[3]));
    float M0 = fmaxf(fmaxf(smx[0], smx[1]), fmaxf(smx[2], smx[3]));
    atomicMin(&mn[n], fl(m0));
    atomicMax(&mx[n], fl(M0));
  }
}

// ---- K4: soft-quant + co-occurrence via MFMA, atomic-free ---------------
__global__ void __launch_bounds__(256) k4_sta(const float* __restrict__ cosb,
                                              const unsigned* __restrict__ mn,
                                              const unsigned* __restrict__ mx,
                                              float* __restrict__ parts){
  int bid = blockIdx.x;              // grid = 16*32 = 512
  int n = bid >> 5, pb = bid & 31;
  int t = threadIdx.x;
  int wv = t >> 6, lane = t & 63;
  int lvl = lane & 15, g = lane >> 4;

  float cmin = unfl(mn[n]), cmax = unfl(mx[n]);
  float q = (float)(2*lvl + 1) * (1.0f/32.0f) * (cmax - cmin) + cmin;
  int h0 = pb*16 + wv*4;
  const float* cosn = cosb + (size_t)n * HWP;

  f32x4 acc = {0.f, 0.f, 0.f, 0.f};
  #pragma unroll 2
  for (int kc = 0; kc < 16; ++kc){
    int px = kc*32 + g*8;
    unsigned qp[5][4];               // 5 rows x 8 quants as packed bf16
    unsigned qx[5];                  // quant of pixel px+8
    bool in8 = (px + 8 <= WW - 1);
    #pragma unroll
    for (int r = 0; r < 5; ++r){
      int hr = h0 + r; if (hr > HH - 1) hr = HH - 1;   // clamp: value unused
      const float* row = cosn + (size_t)hr * WW + px;
      float4 v0 = *(const float4*)row;
      float4 v1 = *(const float4*)(row + 4);
      qp[r][0] = pkbf(qexp(v0.x,q), qexp(v0.y,q));
      qp[r][1] = pkbf(qexp(v0.z,q), qexp(v0.w,q));
      qp[r][2] = pkbf(qexp(v1.x,q), qexp(v1.y,q));
      qp[r][3] = pkbf(qexp(v1.z,q), qexp(v1.w,q));
      float p8 = in8 ? qexp(row[8], q) : 0.0f;  // zero-pad at source px 512
      qx[r] = pkbf(p8, 0.0f);
    }
    #pragma unroll
    for (int r = 0; r < 4; ++r){
      if (h0 + r <= HH - 2){         // wave-uniform; pair (511,512) invalid
        u32x4 aw = {qp[r][0], qp[r][1], qp[r][2], qp[r][3]};
        u32x4 bw = {(qp[r+1][0] >> 16) | (qp[r+1][1] << 16),
                    (qp[r+1][1] >> 16) | (qp[r+1][2] << 16),
                    (qp[r+1][2] >> 16) | (qp[r+1][3] << 16),
                    (qp[r+1][3] >> 16) | (qx[r+1]    << 16)};
        acc = __builtin_amdgcn_mfma_f32_16x16x32_bf16(
                __builtin_bit_cast(short8, aw),
                __builtin_bit_cast(short8, bw), acc, 0, 0, 0);
      }
    }
  }
  // C/D layout: col = lane&15, row = (lane>>4)*4 + reg   [m89-verified]
  __shared__ float sm4[4][256];
  int jo = lane & 15, io0 = (lane >> 4) * 4;
  #pragma unroll
  for (int r = 0; r < 4; ++r) sm4[wv][(io0 + r)*16 + jo] = acc[r];
  __syncthreads();
  parts[(size_t)(n*32 + pb)*256 + t] =
      (sm4[0][t] + sm4[1][t]) + (sm4[2][t] + sm4[3][t]);
}

// ---- K5: reduce partials, normalize sta, emit (N,16,16,3) ---------------
__global__ void __launch_bounds__(256) k5_out(const float* __restrict__ parts,
                                              const unsigned* __restrict__ mn,
                                              const unsigned* __restrict__ mx,
                                              float* __restrict__ out){
  int n = blockIdx.x;                // grid 16 x 256
  int t = threadIdx.x;
  float s = 0.0f;
  #pragma unroll 8
  for (int pb = 0; pb < 32; ++pb) s += parts[(size_t)(n*32 + pb)*256 + t];

  float tot = wred_sum(s);
  __shared__ float sm[4];
  if ((t & 63) == 0) sm[t >> 6] = tot;
  __syncthreads();
  tot = (sm[0] + sm[1]) + (sm[2] + sm[3]);

  float cmin = unfl(mn[n]), cmax = unfl(mx[n]);
  float d = cmax - cmin;
  int i = t >> 4, j = t & 15;
  float qi = (float)(2*i + 1) * (1.0f/32.0f) * d + cmin;
  float qj = (float)(2*j + 1) * (1.0f/32.0f) * d + cmin;
  float* o = out + (size_t)(n*256 + t) * 3;
  o[0] = qj;        // qh[n,i,j] = q_levels[n,j]
  o[1] = qi;        // qw[n,i,j] = q_levels[n,i]
  o[2] = s / tot;   // normalized sta
}

// ---- launch --------------------------------------------------------------
extern "C" void kernel_launch(void* const* d_in, const int* in_sizes, int n_in,
                              void* d_out, int out_size, void* d_ws, size_t ws_size,
                              hipStream_t stream){
  const f32x4* xv = (const f32x4*)d_in[0];
  float* ws   = (float*)d_ws;
  float* sumc = ws + WS_SUMC;
  unsigned* mn = (unsigned*)ws + WS_MIN;
  unsigned* mx = (unsigned*)ws + WS_MAX;
  float* cosb = ws + WS_COS;
  float* parts= ws + WS_PARTS;
  unsigned* codes = (unsigned*)ws + WS_CODES;
  float* out  = (float*)d_out;

  size_t need = ((size_t)WS_CODES + CODES_DW) * 4;
  if (ws_size >= need){
    k1c<<<1024, 256, 0, stream>>>(xv, sumc, codes, mn, mx);
    k2c<<<512,  256, 0, stream>>>(codes, sumc, (f32x4*)cosb, mn, mx);
  } else {
    k1p<<<1024, 256, 0, stream>>>(xv, sumc, mn, mx);
    k2f<<<1024, 256, 0, stream>>>(xv, sumc, (f32x4*)cosb, mn, mx);
  }
  k4_sta<<<512, 256, 0, stream>>>(cosb, mn, mx, parts);
  k5_out<<<16,  256, 0, stream>>>(parts, mn, mx, out);
}

// Round 9
// 378.334 us; speedup vs baseline: 1.3110x; 1.3110x over previous
//
#include <hip/hip_runtime.h>
#include <hip/hip_bf16.h>

// Problem constants: x is (N=16, C=64, H=512, W=512) float32, LEVEL_NUM=16.
#define NB   16
#define CB   64
#define HH   512
#define WW   512
#define HWP  (HH*WW)          // 262144 pixels per (n,c)
#define HWP4 (HWP/4)          // 65536 float4 per (n,c)
#define LEV  16

typedef __attribute__((ext_vector_type(8))) short    short8;
typedef __attribute__((ext_vector_type(4))) float    f32x4;
typedef __attribute__((ext_vector_type(4))) unsigned u32x4;

// ---- helpers -------------------------------------------------------------

__device__ inline float wred_sum(float v){
  #pragma unroll
  for (int m = 32; m > 0; m >>= 1) v += __shfl_xor(v, m, 64);
  return v;
}
__device__ inline float wred_min(float v){
  #pragma unroll
  for (int m = 32; m > 0; m >>= 1) v = fminf(v, __shfl_xor(v, m, 64));
  return v;
}
__device__ inline float wred_max(float v){
  #pragma unroll
  for (int m = 32; m > 0; m >>= 1) v = fmaxf(v, __shfl_xor(v, m, 64));
  return v;
}

// monotonic float<->uint mapping so we can use atomicMin/Max on unsigned
__device__ inline unsigned fl(float f){
  unsigned b = __float_as_uint(f);
  return (b & 0x80000000u) ? ~b : (b | 0x80000000u);
}
__device__ inline float unfl(unsigned u){
  unsigned b = (u & 0x80000000u) ? (u ^ 0x80000000u) : ~u;
  return __uint_as_float(b);
}

#define C3 (-0.022542110013890053f)   // -(sigma^2)*log2(e), sigma^2 = 1/64

__device__ inline float qexp(float v, float q){
  float d = v - q; return exp2f(C3 * d * d);
}
// pack two f32 -> one u32 of 2x bf16 (RNE) via hardware v_cvt_pk_bf16_f32
__device__ inline unsigned pkbf(float a, float b){
  __hip_bfloat162 h = __float22bfloat162_rn(float2{a, b});
  unsigned u; __builtin_memcpy(&u, &h, sizeof(u));
  return u;
}

// ---- ws layout (float offsets) ------------------------------------------
#define WS_SUMC  0                        // 1024 per-(n,c) channel sums
#define WS_MIN   2048                     // 16 uint (flipped)
#define WS_MAX   2064                     // 16 uint (flipped)
#define WS_COS   8192                     // 16*262144 cos map
#define WS_PARTS (WS_COS + NB*HWP)        // 512*256 sta partials

// ---- K1: per-(n,c) plane sums (first 1 GiB read). Also inits mn/mx. -----
__global__ void __launch_bounds__(256) k1_sums(const f32x4* __restrict__ xv,
                                               float* __restrict__ sumc,
                                               unsigned* __restrict__ mn,
                                               unsigned* __restrict__ mx){
  int nc = blockIdx.x;               // grid = 1024, one block per (n,c) plane
  int t  = threadIdx.x;
  if ((nc & 63) == 0 && t == 0){     // first block of each n inits min/max;
    mn[nc >> 6] = 0xFFFFFFFFu;       // k1 fully completes before k2 reads.
    mx[nc >> 6] = 0u;
  }
  const f32x4* xb = xv + (size_t)nc * HWP4 + t;
  float s = 0.0f;
  #pragma unroll 8
  for (int k = 0; k < 256; ++k){
    f32x4 v = __builtin_nontemporal_load(xb + k*256);
    s += (v[0] + v[1]) + (v[2] + v[3]);
  }
  s = wred_sum(s);
  __shared__ float sm[4];
  if ((t & 63) == 0) sm[t >> 6] = s;
  __syncthreads();
  if (t == 0) sumc[nc] = (sm[0]+sm[1])+(sm[2]+sm[3]);
}

// ---- K2: cosine map + per-n min/max (second 1 GiB read) ----------------
// 4-channel groups: 16 f32x4 loads issued before their FMAs (deep ILP);
// block-rotated channel order decorrelates the 1024 blocks' read targets.
__global__ void __launch_bounds__(256) k2_cos(const f32x4* __restrict__ xv,
                                              const float* __restrict__ sumc,
                                              f32x4* __restrict__ cosv,
                                              unsigned* __restrict__ mn,
                                              unsigned* __restrict__ mx){
  int bid = blockIdx.x;              // grid = 16*64 = 1024
  int n = bid >> 6, ch = bid & 63;
  int t = threadIdx.x;
  int p0 = ch * 1024;
  __shared__ float sa[CB];
  if (t < CB){                       // wave 0: normalized x_ave from sumc
    float val = sumc[n*CB + t] * (1.0f / (float)HWP);
    float s2 = wred_sum(val * val);
    sa[t] = val * (1.0f / fmaxf(sqrtf(s2), 1e-12f));
  }
  __syncthreads();

  f32x4 dot[4], nrm[4];
  #pragma unroll
  for (int k = 0; k < 4; ++k){ dot[k] = (f32x4){0,0,0,0}; nrm[k] = (f32x4){0,0,0,0}; }

  const f32x4* xn = xv + (size_t)n * CB * HWP4 + p0 + t;
  for (int cc = 0; cc < CB; cc += 4){
    f32x4 v[4][4];
    float a[4];
    #pragma unroll
    for (int j = 0; j < 4; ++j){
      int c = (cc + j + ch) & 63;    // rotated start, full coverage
      const f32x4* xb = xn + (size_t)c * HWP4;
      a[j] = sa[c];
      #pragma unroll
      for (int k = 0; k < 4; ++k)
        v[j][k] = __builtin_nontemporal_load(xb + k*256);
    }
    #pragma unroll
    for (int j = 0; j < 4; ++j){
      #pragma unroll
      for (int k = 0; k < 4; ++k){
        dot[k] += a[j] * v[j][k];
        nrm[k] += v[j][k] * v[j][k];
      }
    }
  }

  float mnl = 2.0f, mxl = -2.0f;
  #pragma unroll
  for (int k = 0; k < 4; ++k){
    f32x4 cs;
    #pragma unroll
    for (int e = 0; e < 4; ++e){
      cs[e] = dot[k][e] / fmaxf(sqrtf(nrm[k][e]), 1e-12f);
      mnl = fminf(mnl, cs[e]); mxl = fmaxf(mxl, cs[e]);
    }
    cosv[(size_t)n * HWP4 + p0 + k*256 + t] = cs;
  }

  mnl = wred_min(mnl); mxl = wred_max(mxl);
  __shared__ float smn[4], smx[4];
  if ((t & 63) == 0){ smn[t >> 6] = mnl; smx[t >> 6] = mxl; }
  __syncthreads();
  if (t == 0){
    float m0 = fminf(fminf(smn[0], smn[1]), fminf(smn[2], smn[3]));
    float M0 = fmaxf(fmaxf(smx[0], smx[1]), fmaxf(smx[2], smx[3]));
    atomicMin(&mn[n], fl(m0));
    atomicMax(&mx[n], fl(M0));
  }
}

// ---- K4: soft-quant + co-occurrence via MFMA, atomic-free ---------------
// Wave owns 4 row-pairs (rows h0..h0+4). Per 32-pixel chunk it computes the
// quant levels of each of the 5 rows ONCE, reuses them as A (rows r) and
// 1-pixel-shifted B (rows r+1) via packed 16-bit shifts. All 4 pairs
// accumulate into one 16x16 AGPR tile; 4 waves LDS-reduce to one partial.
__global__ void __launch_bounds__(256) k4_sta(const float* __restrict__ cosb,
                                              const unsigned* __restrict__ mn,
                                              const unsigned* __restrict__ mx,
                                              float* __restrict__ parts){
  int bid = blockIdx.x;              // grid = 16*32 = 512
  int n = bid >> 5, pb = bid & 31;
  int t = threadIdx.x;
  int wv = t >> 6, lane = t & 63;
  int lvl = lane & 15, g = lane >> 4;

  float cmin = unfl(mn[n]), cmax = unfl(mx[n]);
  float q = (float)(2*lvl + 1) * (1.0f/32.0f) * (cmax - cmin) + cmin;
  int h0 = pb*16 + wv*4;
  const float* cosn = cosb + (size_t)n * HWP;

  f32x4 acc = {0.f, 0.f, 0.f, 0.f};
  #pragma unroll 2
  for (int kc = 0; kc < 16; ++kc){
    int px = kc*32 + g*8;
    unsigned qp[5][4];               // 5 rows x 8 quants as packed bf16
    unsigned qx[5];                  // quant of pixel px+8
    bool in8 = (px + 8 <= WW - 1);
    #pragma unroll
    for (int r = 0; r < 5; ++r){
      int hr = h0 + r; if (hr > HH - 1) hr = HH - 1;   // clamp: value unused
      const float* row = cosn + (size_t)hr * WW + px;
      float4 v0 = *(const float4*)row;
      float4 v1 = *(const float4*)(row + 4);
      qp[r][0] = pkbf(qexp(v0.x,q), qexp(v0.y,q));
      qp[r][1] = pkbf(qexp(v0.z,q), qexp(v0.w,q));
      qp[r][2] = pkbf(qexp(v1.x,q), qexp(v1.y,q));
      qp[r][3] = pkbf(qexp(v1.z,q), qexp(v1.w,q));
      float p8 = in8 ? qexp(row[8], q) : 0.0f;  // zero-pad at source px 512
      qx[r] = pkbf(p8, 0.0f);
    }
    #pragma unroll
    for (int r = 0; r < 4; ++r){
      if (h0 + r <= HH - 2){         // wave-uniform; pair (511,512) invalid
        u32x4 aw = {qp[r][0], qp[r][1], qp[r][2], qp[r][3]};
        u32x4 bw = {(qp[r+1][0] >> 16) | (qp[r+1][1] << 16),
                    (qp[r+1][1] >> 16) | (qp[r+1][2] << 16),
                    (qp[r+1][2] >> 16) | (qp[r+1][3] << 16),
                    (qp[r+1][3] >> 16) | (qx[r+1]    << 16)};
        acc = __builtin_amdgcn_mfma_f32_16x16x32_bf16(
                __builtin_bit_cast(short8, aw),
                __builtin_bit_cast(short8, bw), acc, 0, 0, 0);
      }
    }
  }
  // C/D layout: col = lane&15, row = (lane>>4)*4 + reg   [m89-verified]
  __shared__ float sm4[4][256];
  int jo = lane & 15, io0 = (lane >> 4) * 4;
  #pragma unroll
  for (int r = 0; r < 4; ++r) sm4[wv][(io0 + r)*16 + jo] = acc[r];
  __syncthreads();
  parts[(size_t)(n*32 + pb)*256 + t] =
      (sm4[0][t] + sm4[1][t]) + (sm4[2][t] + sm4[3][t]);
}

// ---- K5: reduce partials, normalize sta, emit (N,16,16,3) ---------------
__global__ void __launch_bounds__(256) k5_out(const float* __restrict__ parts,
                                              const unsigned* __restrict__ mn,
                                              const unsigned* __restrict__ mx,
                                              float* __restrict__ out){
  int n = blockIdx.x;                // grid 16 x 256
  int t = threadIdx.x;
  float s = 0.0f;
  #pragma unroll 8
  for (int pb = 0; pb < 32; ++pb) s += parts[(size_t)(n*32 + pb)*256 + t];

  float tot = wred_sum(s);
  __shared__ float sm[4];
  if ((t & 63) == 0) sm[t >> 6] = tot;
  __syncthreads();
  tot = (sm[0] + sm[1]) + (sm[2] + sm[3]);

  float cmin = unfl(mn[n]), cmax = unfl(mx[n]);
  float d = cmax - cmin;
  int i = t >> 4, j = t & 15;
  float qi = (float)(2*i + 1) * (1.0f/32.0f) * d + cmin;
  float qj = (float)(2*j + 1) * (1.0f/32.0f) * d + cmin;
  float* o = out + (size_t)(n*256 + t) * 3;
  o[0] = qj;        // qh[n,i,j] = q_levels[n,j]
  o[1] = qi;        // qw[n,i,j] = q_levels[n,i]
  o[2] = s / tot;   // normalized sta
}

// ---- launch --------------------------------------------------------------
extern "C" void kernel_launch(void* const* d_in, const int* in_sizes, int n_in,
                              void* d_out, int out_size, void* d_ws, size_t ws_size,
                              hipStream_t stream){
  const f32x4* xv = (const f32x4*)d_in[0];
  float* ws   = (float*)d_ws;
  float* sumc = ws + WS_SUMC;
  unsigned* mn = (unsigned*)ws + WS_MIN;
  unsigned* mx = (unsigned*)ws + WS_MAX;
  float* cosb = ws + WS_COS;
  float* parts= ws + WS_PARTS;
  float* out  = (float*)d_out;

  k1_sums <<<1024, 256, 0, stream>>>(xv, sumc, mn, mx);
  k2_cos  <<<1024, 256, 0, stream>>>(xv, sumc, (f32x4*)cosb, mn, mx);
  k4_sta  <<<512,  256, 0, stream>>>(cosb, mn, mx, parts);
  k5_out  <<<16,   256, 0, stream>>>(parts, mn, mx, out);
}